// Round 7
// baseline (242.338 us; speedup 1.0000x reference)
//
#include <hip/hip_runtime.h>
#include <cstdint>

// Problem constants (from reference)
constexpr int B_   = 4096;
constexpr int T_   = 512;
constexpr int DIN  = 10;
constexpr int H_   = 20;
constexpr int DOUT = 2;

constexpr int SPW = 2;            // samples per chain (2 x 20 = 40 active lanes)
constexpr int NCH = 2;            // chains per wave (A, B)
constexpr int CH  = 2;            // timesteps per x-chunk per chain
constexpr int XV  = CH * DIN / 4; // 5 float4 prefetch regs per chain

// Compiler-only memory fence: pins LDS op ordering for wave-synchronous
// exchange (single-wave workgroup; same-wave DS ops execute in order in HW).
#define CFENCE() asm volatile("" ::: "memory")

__device__ __forceinline__ float fast_tanh(float v) {
    // tanh(v) = 1 - 2/(exp2(2*log2e*v)+1): exact saturation at +/-inf
    float e = __builtin_amdgcn_exp2f(v * 2.885390082f);
    float r = __builtin_amdgcn_rcpf(e + 1.0f);
    return fmaf(-2.0f, r, 1.0f);
}

// Two independent skewed RNN chains per wave. Per step tau, per chain:
//   h1(tau)   = tanh(xp[tau] + wh0 . h1(tau-1))
//   h2(tau-1) = tanh(bias1 + wi1 . h1(tau-1) + wh1 . h2(tau-2))
// Schedule: computeA, writeA, computeB, writeB, readA, readB -> each chain's
// LDS round-trip latency hides under the other chain's register-only compute.
extern "C" __global__ void __launch_bounds__(64, 1)
rnn_dual(const float* __restrict__ x,
         const float* __restrict__ w_ih0, const float* __restrict__ w_hh0,
         const float* __restrict__ b_ih0, const float* __restrict__ b_hh0,
         const float* __restrict__ w_ih1, const float* __restrict__ w_hh1,
         const float* __restrict__ b_ih1, const float* __restrict__ b_hh1,
         const float* __restrict__ fc_w, const float* __restrict__ fc_b,
         float* __restrict__ out)
{
    const int lane = threadIdx.x;
    const int sl   = lane / H_;            // 0..1 active, 2..3 idle
    const int i    = lane - sl * H_;       // h-index 0..19
    const bool act = (sl < SPW);
    const int sampA = blockIdx.x * (SPW * NCH) + sl;          // chain A sample
    const int sampB = sampA + SPW;                            // chain B sample
    const int scA = act ? min(sampA, B_ - 1) : (B_ - 1);
    const int scB = act ? min(sampB, B_ - 1) : (B_ - 1);
    const int rowA = act ? sl : 4;          // idle lanes -> spare row
    const int rowB = act ? (SPW + sl) : 4;

    __shared__ __align__(16) float h1s[2 * SPW + 1][H_];
    __shared__ __align__(16) float h2s[2 * SPW + 1][H_];

    // ---- per-lane weight rows in registers (shared by both chains) ----
    float wi0[DIN];
    {
        const float2* p = reinterpret_cast<const float2*>(w_ih0 + i * DIN);
        #pragma unroll
        for (int k = 0; k < DIN / 2; ++k) {
            float2 v = p[k];
            wi0[2 * k] = v.x; wi0[2 * k + 1] = v.y;
        }
    }
    float wh0[H_], wi1[H_], wh1[H_];
    {
        const float4* p0 = reinterpret_cast<const float4*>(w_hh0 + i * H_);
        const float4* p1 = reinterpret_cast<const float4*>(w_ih1 + i * H_);
        const float4* p2 = reinterpret_cast<const float4*>(w_hh1 + i * H_);
        #pragma unroll
        for (int k = 0; k < H_ / 4; ++k) {
            float4 a = p0[k]; wh0[4*k]=a.x; wh0[4*k+1]=a.y; wh0[4*k+2]=a.z; wh0[4*k+3]=a.w;
            float4 b = p1[k]; wi1[4*k]=b.x; wi1[4*k+1]=b.y; wi1[4*k+2]=b.z; wi1[4*k+3]=b.w;
            float4 c = p2[k]; wh1[4*k]=c.x; wh1[4*k+1]=c.y; wh1[4*k+2]=c.z; wh1[4*k+3]=c.w;
        }
    }
    const float bias0 = b_ih0[i] + b_hh0[i];
    const float bias1 = b_ih1[i] + b_hh1[i];

    // ---- chain state: h1q = h1(tau-1), h2q = h2(tau-2) ----
    float4 h1qA[H_/4], h2qA[H_/4], h1qB[H_/4], h2qB[H_/4];
    #pragma unroll
    for (int k = 0; k < H_ / 4; ++k) {
        h1qA[k] = make_float4(0.f,0.f,0.f,0.f); h2qA[k] = make_float4(0.f,0.f,0.f,0.f);
        h1qB[k] = make_float4(0.f,0.f,0.f,0.f); h2qB[k] = make_float4(0.f,0.f,0.f,0.f);
    }

    const float4* xbA = reinterpret_cast<const float4*>(x + (size_t)scA * (T_ * DIN));
    const float4* xbB = reinterpret_cast<const float4*>(x + (size_t)scB * (T_ * DIN));

    // ---- prefetch chunk 0 for both chains ----
    float4 xvA[XV], xvB[XV];
    #pragma unroll
    for (int k = 0; k < XV; ++k) { xvA[k] = xbA[k]; xvB[k] = xbB[k]; }

    // register-only compute of one chain's skewed step
    auto compute2 = [&](const float4 (&h1q)[H_/4], const float4 (&h2q)[H_/4],
                        float xpm, float& h1n, float& h2n) {
        float a0 = xpm, a1 = 0.f, a2 = 0.f, a3 = 0.f;
        float b0 = bias1, b1 = 0.f, b2 = 0.f, b3 = 0.f;
        #pragma unroll
        for (int k = 0; k < H_ / 4; ++k) {
            a0 = fmaf(h1q[k].x, wh0[4*k+0], a0);
            a1 = fmaf(h1q[k].y, wh0[4*k+1], a1);
            a2 = fmaf(h1q[k].z, wh0[4*k+2], a2);
            a3 = fmaf(h1q[k].w, wh0[4*k+3], a3);
            b0 = fmaf(h1q[k].x, wi1[4*k+0], b0);
            b1 = fmaf(h1q[k].y, wi1[4*k+1], b1);
            b2 = fmaf(h1q[k].z, wi1[4*k+2], b2);
            b3 = fmaf(h1q[k].w, wi1[4*k+3], b3);
        }
        #pragma unroll
        for (int k = 0; k < H_ / 4; ++k) {
            b0 = fmaf(h2q[k].x, wh1[4*k+0], b0);
            b1 = fmaf(h2q[k].y, wh1[4*k+1], b1);
            b2 = fmaf(h2q[k].z, wh1[4*k+2], b2);
            b3 = fmaf(h2q[k].w, wh1[4*k+3], b3);
        }
        h1n = fast_tanh((a0 + a1) + (a2 + a3));
        h2n = fast_tanh((b0 + b1) + (b2 + b3));
    };

    auto readback = [&](float4 (&h1q)[H_/4], float4 (&h2q)[H_/4], int row) {
        #pragma unroll
        for (int k = 0; k < H_ / 4; ++k)
            h1q[k] = reinterpret_cast<const float4*>(&h1s[row][0])[k];
        #pragma unroll
        for (int k = 0; k < H_ / 4; ++k)
            h2q[k] = reinterpret_cast<const float4*>(&h2s[row][0])[k];
    };

    // interleaved step-pair: A's LDS round-trip hides under B's compute
    auto step_pair = [&](float xpa, float xpb) {
        float h1nA, h2nA, h1nB, h2nB;
        compute2(h1qA, h2qA, xpa, h1nA, h2nA);
        CFENCE();
        h1s[rowA][i] = h1nA; h2s[rowA][i] = h2nA;
        CFENCE();
        compute2(h1qB, h2qB, xpb, h1nB, h2nB);
        CFENCE();
        h1s[rowB][i] = h1nB; h2s[rowB][i] = h2nB;
        CFENCE();
        readback(h1qA, h2qA, rowA);
        CFENCE();
        readback(h1qB, h2qB, rowB);
        CFENCE();
    };

    auto consume_xp = [&](const float4 (&xv)[XV], float (&xp)[CH]) {
        #pragma unroll
        for (int m = 0; m < CH; ++m) xp[m] = bias0;
        #pragma unroll
        for (int k = 0; k < XV; ++k) {
            int idx = 4 * k;
            xp[(idx+0)/DIN] = fmaf(xv[k].x, wi0[(idx+0)%DIN], xp[(idx+0)/DIN]);
            xp[(idx+1)/DIN] = fmaf(xv[k].y, wi0[(idx+1)%DIN], xp[(idx+1)/DIN]);
            xp[(idx+2)/DIN] = fmaf(xv[k].z, wi0[(idx+2)%DIN], xp[(idx+2)/DIN]);
            xp[(idx+3)/DIN] = fmaf(xv[k].w, wi0[(idx+3)%DIN], xp[(idx+3)/DIN]);
        }
    };

    // ---- chunk 0, tau=0 peeled: h1(0)=tanh(xp[0]), h2 untouched ----
    {
        float xpA[CH], xpB[CH];
        consume_xp(xvA, xpA);
        consume_xp(xvB, xpB);
        #pragma unroll
        for (int k = 0; k < XV; ++k) {        // prefetch chunk 1
            xvA[k] = xbA[(CH * DIN) / 4 + k];
            xvB[k] = xbB[(CH * DIN) / 4 + k];
        }
        float h1nA = fast_tanh(xpA[0]);
        float h1nB = fast_tanh(xpB[0]);
        CFENCE();
        h1s[rowA][i] = h1nA; h1s[rowB][i] = h1nB;
        CFENCE();
        #pragma unroll
        for (int k = 0; k < H_ / 4; ++k) {
            h1qA[k] = reinterpret_cast<const float4*>(&h1s[rowA][0])[k];
            h1qB[k] = reinterpret_cast<const float4*>(&h1s[rowB][0])[k];
        }
        CFENCE();
        #pragma unroll
        for (int m = 1; m < CH; ++m) step_pair(xpA[m], xpB[m]);
    }

    // ---- main loop ----
    for (int t0 = CH; t0 < T_; t0 += CH) {
        float xpA[CH], xpB[CH];
        consume_xp(xvA, xpA);
        consume_xp(xvB, xpB);
        {
            const int t0n = (t0 + CH < T_) ? (t0 + CH) : 0;   // clamp, branchless
            const int base = t0n * DIN / 4;
            #pragma unroll
            for (int k = 0; k < XV; ++k) { xvA[k] = xbA[base + k]; xvB[k] = xbB[base + k]; }
        }
        #pragma unroll
        for (int m = 0; m < CH; ++m) step_pair(xpA[m], xpB[m]);
    }

    // ---- epilogue: h2(T-1) per chain from h1(T-1), h2(T-2) ----
    {
        auto fin = [&](const float4 (&h1q)[H_/4], const float4 (&h2q)[H_/4]) -> float {
            float b0 = bias1, b1 = 0.f, b2 = 0.f, b3 = 0.f;
            #pragma unroll
            for (int k = 0; k < H_ / 4; ++k) {
                b0 = fmaf(h1q[k].x, wi1[4*k+0], b0);
                b1 = fmaf(h1q[k].y, wi1[4*k+1], b1);
                b2 = fmaf(h1q[k].z, wi1[4*k+2], b2);
                b3 = fmaf(h1q[k].w, wi1[4*k+3], b3);
            }
            #pragma unroll
            for (int k = 0; k < H_ / 4; ++k) {
                b0 = fmaf(h2q[k].x, wh1[4*k+0], b0);
                b1 = fmaf(h2q[k].y, wh1[4*k+1], b1);
                b2 = fmaf(h2q[k].z, wh1[4*k+2], b2);
                b3 = fmaf(h2q[k].w, wh1[4*k+3], b3);
            }
            return fast_tanh((b0 + b1) + (b2 + b3));
        };
        float h2nA = fin(h1qA, h2qA);
        float h2nB = fin(h1qB, h2qB);
        CFENCE();
        h2s[rowA][i] = h2nA; h2s[rowB][i] = h2nB;
        CFENCE();
        #pragma unroll
        for (int k = 0; k < H_ / 4; ++k) {
            h2qA[k] = reinterpret_cast<const float4*>(&h2s[rowA][0])[k];
            h2qB[k] = reinterpret_cast<const float4*>(&h2s[rowB][0])[k];
        }
        CFENCE();
    }

    // ---- FC: lanes sl<2, i<2 hold full final h2 per chain ----
    if (act && i < DOUT) {
        float accA = fc_b[i], accB = fc_b[i];
        #pragma unroll
        for (int k = 0; k < H_ / 4; ++k) {
            accA = fmaf(h2qA[k].x, fc_w[i*H_ + 4*k+0], accA);
            accA = fmaf(h2qA[k].y, fc_w[i*H_ + 4*k+1], accA);
            accA = fmaf(h2qA[k].z, fc_w[i*H_ + 4*k+2], accA);
            accA = fmaf(h2qA[k].w, fc_w[i*H_ + 4*k+3], accA);
            accB = fmaf(h2qB[k].x, fc_w[i*H_ + 4*k+0], accB);
            accB = fmaf(h2qB[k].y, fc_w[i*H_ + 4*k+1], accB);
            accB = fmaf(h2qB[k].z, fc_w[i*H_ + 4*k+2], accB);
            accB = fmaf(h2qB[k].w, fc_w[i*H_ + 4*k+3], accB);
        }
        if (sampA < B_) out[sampA * DOUT + i] = accA;
        if (sampB < B_) out[sampB * DOUT + i] = accB;
    }
}

extern "C" void kernel_launch(void* const* d_in, const int* in_sizes, int n_in,
                              void* d_out, int out_size, void* d_ws, size_t ws_size,
                              hipStream_t stream) {
    (void)in_sizes; (void)n_in; (void)d_ws; (void)ws_size; (void)out_size;
    const float* x     = (const float*)d_in[0];
    const float* w_ih0 = (const float*)d_in[1];
    const float* w_hh0 = (const float*)d_in[2];
    const float* b_ih0 = (const float*)d_in[3];
    const float* b_hh0 = (const float*)d_in[4];
    const float* w_ih1 = (const float*)d_in[5];
    const float* w_hh1 = (const float*)d_in[6];
    const float* b_ih1 = (const float*)d_in[7];
    const float* b_hh1 = (const float*)d_in[8];
    const float* fc_w  = (const float*)d_in[9];
    const float* fc_b  = (const float*)d_in[10];
    float* out = (float*)d_out;

    const int grid = B_ / (SPW * NCH);   // 1024 single-wave blocks = 1 wave/SIMD
    hipLaunchKernelGGL(rnn_dual, dim3(grid), dim3(64), 0, stream,
                       x, w_ih0, w_hh0, b_ih0, b_hh0,
                       w_ih1, w_hh1, b_ih1, b_hh1, fc_w, fc_b, out);
}

// Round 8
// 156.254 us; speedup vs baseline: 1.5509x; 1.5509x over previous
//
#include <hip/hip_runtime.h>
#include <cstdint>

// Problem constants (from reference)
constexpr int B_   = 4096;
constexpr int T_   = 512;
constexpr int DIN  = 10;
constexpr int H_   = 20;
constexpr int DOUT = 2;

constexpr int SPW = 3;            // samples per wave (3 x 20 = 60 active lanes)
constexpr int CH  = 4;            // timesteps per x-chunk (4*10 floats = 10 float4)
constexpr int XV  = CH * DIN / 4; // float4 prefetch regs per chunk

// Compiler-only memory fence: pins LDS op ordering for wave-synchronous
// exchange (single-wave workgroup; same-wave DS ops execute in order in HW).
#define CFENCE() asm volatile("" ::: "memory")

__device__ __forceinline__ float fast_tanh(float v) {
    // tanh(v) = 1 - 2/(exp2(2*log2e*v)+1): exact saturation at +/-inf
    float e = __builtin_amdgcn_exp2f(v * 2.885390082f);
    float r = __builtin_amdgcn_rcpf(e + 1.0f);
    return fmaf(-2.0f, r, 1.0f);
}

// Skewed 2-layer RNN, latency-ordered step:
//   phase 1 (critical): h1(tau) = tanh(xp + wh0 . h1(tau-1));  write h1
//   phase 2 (cover):    h2(tau-1) = tanh(bias1 + wi1 . h1(tau-1) + wh1 . h2(tau-2)); write h2
//   phase 3:            readback h1, h2
// Phase 2's ~50 FMA + tanh sits inside h1's LDS write->read window, so the
// only exposed latency per step is the tail of the round-trip.
extern "C" __global__ void __launch_bounds__(64, 1)
rnn_skew2(const float* __restrict__ x,
          const float* __restrict__ w_ih0, const float* __restrict__ w_hh0,
          const float* __restrict__ b_ih0, const float* __restrict__ b_hh0,
          const float* __restrict__ w_ih1, const float* __restrict__ w_hh1,
          const float* __restrict__ b_ih1, const float* __restrict__ b_hh1,
          const float* __restrict__ fc_w, const float* __restrict__ fc_b,
          float* __restrict__ out)
{
    const int lane = threadIdx.x;
    const int sl   = lane / H_;          // 0..2 active, 3 = idle lanes 60..63
    const int i    = lane - sl * H_;     // h-index 0..19
    const int samp = blockIdx.x * SPW + sl;
    const int sc   = (samp < B_) ? samp : (B_ - 1);   // clamped for safe loads
    const int slc  = (sl < SPW) ? sl : SPW;           // idle lanes -> spare row

    __shared__ __align__(16) float h1s[SPW + 1][H_];
    __shared__ __align__(16) float h2s[SPW + 1][H_];

    // ---- per-lane weight rows in registers (loop-invariant) ----
    float wi0[DIN];
    {
        const float2* p = reinterpret_cast<const float2*>(w_ih0 + i * DIN);
        #pragma unroll
        for (int k = 0; k < DIN / 2; ++k) {
            float2 v = p[k];
            wi0[2 * k] = v.x; wi0[2 * k + 1] = v.y;
        }
    }
    float wh0[H_], wi1[H_], wh1[H_];
    {
        const float4* p0 = reinterpret_cast<const float4*>(w_hh0 + i * H_);
        const float4* p1 = reinterpret_cast<const float4*>(w_ih1 + i * H_);
        const float4* p2 = reinterpret_cast<const float4*>(w_hh1 + i * H_);
        #pragma unroll
        for (int k = 0; k < H_ / 4; ++k) {
            float4 a = p0[k]; wh0[4*k]=a.x; wh0[4*k+1]=a.y; wh0[4*k+2]=a.z; wh0[4*k+3]=a.w;
            float4 b = p1[k]; wi1[4*k]=b.x; wi1[4*k+1]=b.y; wi1[4*k+2]=b.z; wi1[4*k+3]=b.w;
            float4 c = p2[k]; wh1[4*k]=c.x; wh1[4*k+1]=c.y; wh1[4*k+2]=c.z; wh1[4*k+3]=c.w;
        }
    }
    const float bias0 = b_ih0[i] + b_hh0[i];
    const float bias1 = b_ih1[i] + b_hh1[i];

    // ---- register state: h1q = h1(tau-1), h2q = h2(tau-2) ----
    float4 h1q[H_ / 4], h2q[H_ / 4];
    #pragma unroll
    for (int k = 0; k < H_ / 4; ++k) {
        h1q[k] = make_float4(0.f, 0.f, 0.f, 0.f);
        h2q[k] = make_float4(0.f, 0.f, 0.f, 0.f);
    }

    const float4* xb = reinterpret_cast<const float4*>(x + (size_t)sc * (T_ * DIN));

    // ---- prologue: prefetch chunk 0 ----
    float4 xv[XV];
    #pragma unroll
    for (int k = 0; k < XV; ++k) xv[k] = xb[k];

    // one latency-ordered skewed step
    auto full_step = [&](float xpm) {
        // ---- phase 1: critical L0 dot + tanh + h1 write ----
        float a0 = xpm, a1 = 0.f, a2 = 0.f, a3 = 0.f;
        #pragma unroll
        for (int k = 0; k < H_ / 4; ++k) {
            a0 = fmaf(h1q[k].x, wh0[4*k+0], a0);
            a1 = fmaf(h1q[k].y, wh0[4*k+1], a1);
            a2 = fmaf(h1q[k].z, wh0[4*k+2], a2);
            a3 = fmaf(h1q[k].w, wh0[4*k+3], a3);
        }
        float h1n = fast_tanh((a0 + a1) + (a2 + a3));
        CFENCE();
        h1s[slc][i] = h1n;          // ds_write issued早; RT hides under phase 2
        CFENCE();

        // ---- phase 2: L1 (skewed; register-only inputs) covers the RT ----
        float b0 = bias1, b1 = 0.f, b2 = 0.f, b3 = 0.f;
        #pragma unroll
        for (int k = 0; k < H_ / 4; ++k) {
            b0 = fmaf(h1q[k].x, wi1[4*k+0], b0);
            b1 = fmaf(h1q[k].y, wi1[4*k+1], b1);
            b2 = fmaf(h1q[k].z, wi1[4*k+2], b2);
            b3 = fmaf(h1q[k].w, wi1[4*k+3], b3);
        }
        #pragma unroll
        for (int k = 0; k < H_ / 4; ++k) {
            b0 = fmaf(h2q[k].x, wh1[4*k+0], b0);
            b1 = fmaf(h2q[k].y, wh1[4*k+1], b1);
            b2 = fmaf(h2q[k].z, wh1[4*k+2], b2);
            b3 = fmaf(h2q[k].w, wh1[4*k+3], b3);
        }
        float h2n = fast_tanh((b0 + b1) + (b2 + b3));
        CFENCE();
        h2s[slc][i] = h2n;
        CFENCE();

        // ---- phase 3: batched readbacks (h1 ready; h2 covered by next L0) ----
        #pragma unroll
        for (int k = 0; k < H_ / 4; ++k)
            h1q[k] = reinterpret_cast<const float4*>(&h1s[slc][0])[k];
        #pragma unroll
        for (int k = 0; k < H_ / 4; ++k)
            h2q[k] = reinterpret_cast<const float4*>(&h2s[slc][0])[k];
        CFENCE();
    };

    // consume xv -> xp for a chunk
    auto consume_xp = [&](float (&xp)[CH]) {
        #pragma unroll
        for (int m = 0; m < CH; ++m) xp[m] = bias0;
        #pragma unroll
        for (int k = 0; k < XV; ++k) {
            int idx = 4 * k;
            xp[(idx+0)/DIN] = fmaf(xv[k].x, wi0[(idx+0)%DIN], xp[(idx+0)/DIN]);
            xp[(idx+1)/DIN] = fmaf(xv[k].y, wi0[(idx+1)%DIN], xp[(idx+1)/DIN]);
            xp[(idx+2)/DIN] = fmaf(xv[k].z, wi0[(idx+2)%DIN], xp[(idx+2)/DIN]);
            xp[(idx+3)/DIN] = fmaf(xv[k].w, wi0[(idx+3)%DIN], xp[(idx+3)/DIN]);
        }
    };

    // ---- chunk 0 (tau = 0..CH-1), tau=0 peeled: h1(0)=tanh(xp[0]) ----
    {
        float xp[CH];
        consume_xp(xp);
        #pragma unroll
        for (int k = 0; k < XV; ++k) xv[k] = xb[(CH * DIN) / 4 + k];  // prefetch chunk 1

        float h1n = fast_tanh(xp[0]);
        CFENCE();
        h1s[slc][i] = h1n;
        CFENCE();
        #pragma unroll
        for (int k = 0; k < H_ / 4; ++k)
            h1q[k] = reinterpret_cast<const float4*>(&h1s[slc][0])[k];
        CFENCE();

        #pragma unroll
        for (int m = 1; m < CH; ++m) full_step(xp[m]);
    }

    // ---- main loop: chunks t0 = CH .. T-CH ----
    for (int t0 = CH; t0 < T_; t0 += CH) {
        float xp[CH];
        consume_xp(xp);
        {
            const int t0n = (t0 + CH < T_) ? (t0 + CH) : 0;  // clamp, branchless
            #pragma unroll
            for (int k = 0; k < XV; ++k) xv[k] = xb[(t0n * DIN) / 4 + k];
        }
        #pragma unroll
        for (int m = 0; m < CH; ++m) full_step(xp[m]);
    }

    // ---- epilogue: h2(T-1) from h1(T-1) (=h1q) and h2(T-2) (=h2q) ----
    {
        float b0 = bias1, b1 = 0.f, b2 = 0.f, b3 = 0.f;
        #pragma unroll
        for (int k = 0; k < H_ / 4; ++k) {
            b0 = fmaf(h1q[k].x, wi1[4*k+0], b0);
            b1 = fmaf(h1q[k].y, wi1[4*k+1], b1);
            b2 = fmaf(h1q[k].z, wi1[4*k+2], b2);
            b3 = fmaf(h1q[k].w, wi1[4*k+3], b3);
        }
        #pragma unroll
        for (int k = 0; k < H_ / 4; ++k) {
            b0 = fmaf(h2q[k].x, wh1[4*k+0], b0);
            b1 = fmaf(h2q[k].y, wh1[4*k+1], b1);
            b2 = fmaf(h2q[k].z, wh1[4*k+2], b2);
            b3 = fmaf(h2q[k].w, wh1[4*k+3], b3);
        }
        float h2n = fast_tanh((b0 + b1) + (b2 + b3));
        CFENCE();
        h2s[slc][i] = h2n;
        CFENCE();
        #pragma unroll
        for (int k = 0; k < H_ / 4; ++k)
            h2q[k] = reinterpret_cast<const float4*>(&h2s[slc][0])[k];
        CFENCE();
    }

    // ---- FC: lanes i<2 hold full h2(T-1); out[samp][i] ----
    if (sl < SPW && samp < B_ && i < DOUT) {
        float hf[H_];
        #pragma unroll
        for (int k = 0; k < H_ / 4; ++k) {
            hf[4*k+0] = h2q[k].x; hf[4*k+1] = h2q[k].y;
            hf[4*k+2] = h2q[k].z; hf[4*k+3] = h2q[k].w;
        }
        float acc = fc_b[i];
        #pragma unroll
        for (int j = 0; j < H_; ++j) acc = fmaf(hf[j], fc_w[i * H_ + j], acc);
        out[samp * DOUT + i] = acc;
    }
}

extern "C" void kernel_launch(void* const* d_in, const int* in_sizes, int n_in,
                              void* d_out, int out_size, void* d_ws, size_t ws_size,
                              hipStream_t stream) {
    (void)in_sizes; (void)n_in; (void)d_ws; (void)ws_size; (void)out_size;
    const float* x     = (const float*)d_in[0];
    const float* w_ih0 = (const float*)d_in[1];
    const float* w_hh0 = (const float*)d_in[2];
    const float* b_ih0 = (const float*)d_in[3];
    const float* b_hh0 = (const float*)d_in[4];
    const float* w_ih1 = (const float*)d_in[5];
    const float* w_hh1 = (const float*)d_in[6];
    const float* b_ih1 = (const float*)d_in[7];
    const float* b_hh1 = (const float*)d_in[8];
    const float* fc_w  = (const float*)d_in[9];
    const float* fc_b  = (const float*)d_in[10];
    float* out = (float*)d_out;

    const int grid = (B_ + SPW - 1) / SPW;   // 1366 single-wave blocks
    hipLaunchKernelGGL(rnn_skew2, dim3(grid), dim3(64), 0, stream,
                       x, w_ih0, w_hh0, b_ih0, b_hh0,
                       w_ih1, w_hh1, b_ih1, b_hh1, fc_w, fc_b, out);
}

// Round 9
// 144.282 us; speedup vs baseline: 1.6796x; 1.0830x over previous
//
#include <hip/hip_runtime.h>
#include <cstdint>

// Problem constants (from reference)
constexpr int B_   = 4096;
constexpr int T_   = 512;
constexpr int DIN  = 10;
constexpr int H_   = 20;
constexpr int DOUT = 2;

constexpr int SPW = 3;            // samples per wave (3 x 20 = 60 active lanes)
constexpr int CH  = 4;            // timesteps per x-chunk (4*10 floats = 10 float4)
constexpr int XV  = CH * DIN / 4; // float4 prefetch regs per chunk

typedef float v2f __attribute__((ext_vector_type(2)));
typedef float v4f __attribute__((ext_vector_type(4)));

// Compiler-only memory fence: pins LDS op ordering for wave-synchronous
// exchange (single-wave workgroup; same-wave DS ops execute in order in HW).
#define CFENCE() asm volatile("" ::: "memory")

// One v_pk_fma_f32: two fp32 FMAs per instruction (gfx950 packed-FP32).
__device__ __forceinline__ v2f pkfma(v2f a, v2f b, v2f c) {
    return __builtin_elementwise_fma(a, b, c);
}
__device__ __forceinline__ v2f lohalf(v4f v) { return __builtin_shufflevector(v, v, 0, 1); }
__device__ __forceinline__ v2f hihalf(v4f v) { return __builtin_shufflevector(v, v, 2, 3); }

__device__ __forceinline__ float fast_tanh(float v) {
    // tanh(v) = 1 - 2/(exp2(2*log2e*v)+1): exact saturation at +/-inf
    float e = __builtin_amdgcn_exp2f(v * 2.885390082f);
    float r = __builtin_amdgcn_rcpf(e + 1.0f);
    return fmaf(-2.0f, r, 1.0f);
}

// Skewed 2-layer RNN with packed-fp32 dots:
//   h1(tau)   = tanh(xp[tau] + wh0 . h1(tau-1))
//   h2(tau-1) = tanh(bias1 + wi1 . h1(tau-1) + wh1 . h2(tau-2))
// All dot products run as v_pk_fma_f32 on float2 pairs (35 pk-ops vs 70
// scalar FMAs per step); one batched LDS exchange per step.
extern "C" __global__ void __launch_bounds__(64, 1)
rnn_pk(const float* __restrict__ x,
       const float* __restrict__ w_ih0, const float* __restrict__ w_hh0,
       const float* __restrict__ b_ih0, const float* __restrict__ b_hh0,
       const float* __restrict__ w_ih1, const float* __restrict__ w_hh1,
       const float* __restrict__ b_ih1, const float* __restrict__ b_hh1,
       const float* __restrict__ fc_w, const float* __restrict__ fc_b,
       float* __restrict__ out)
{
    const int lane = threadIdx.x;
    const int sl   = lane / H_;          // 0..2 active, 3 = idle lanes 60..63
    const int i    = lane - sl * H_;     // h-index 0..19
    const int samp = blockIdx.x * SPW + sl;
    const int sc   = (samp < B_) ? samp : (B_ - 1);   // clamped for safe loads
    const int slc  = (sl < SPW) ? sl : SPW;           // idle lanes -> spare row

    __shared__ __align__(16) float h1s[SPW + 1][H_];
    __shared__ __align__(16) float h2s[SPW + 1][H_];

    // ---- per-lane weight rows as float2 pairs (loop-invariant) ----
    v2f wi0p[DIN / 2];
    {
        const v2f* p = reinterpret_cast<const v2f*>(w_ih0 + i * DIN);
        #pragma unroll
        for (int k = 0; k < DIN / 2; ++k) wi0p[k] = p[k];
    }
    v2f wh0p[H_ / 2], wi1p[H_ / 2], wh1p[H_ / 2];
    {
        const v4f* p0 = reinterpret_cast<const v4f*>(w_hh0 + i * H_);
        const v4f* p1 = reinterpret_cast<const v4f*>(w_ih1 + i * H_);
        const v4f* p2 = reinterpret_cast<const v4f*>(w_hh1 + i * H_);
        #pragma unroll
        for (int k = 0; k < H_ / 4; ++k) {
            v4f a = p0[k]; wh0p[2*k] = lohalf(a); wh0p[2*k+1] = hihalf(a);
            v4f b = p1[k]; wi1p[2*k] = lohalf(b); wi1p[2*k+1] = hihalf(b);
            v4f c = p2[k]; wh1p[2*k] = lohalf(c); wh1p[2*k+1] = hihalf(c);
        }
    }
    const float bias0 = b_ih0[i] + b_hh0[i];
    const float bias1 = b_ih1[i] + b_hh1[i];

    // ---- register state as pairs: h1p = h1(tau-1), h2p = h2(tau-2) ----
    v2f h1p[H_ / 2], h2p[H_ / 2];
    #pragma unroll
    for (int k = 0; k < H_ / 2; ++k) {
        h1p[k] = (v2f){0.f, 0.f};
        h2p[k] = (v2f){0.f, 0.f};
    }

    const v4f* xb = reinterpret_cast<const v4f*>(x + (size_t)sc * (T_ * DIN));

    // ---- prologue: prefetch chunk 0 ----
    v4f xv[XV];
    #pragma unroll
    for (int k = 0; k < XV; ++k) xv[k] = xb[k];

    // x-pair p (global float pair index within chunk) from xv
    auto getpair = [&](int p) -> v2f {
        v4f v = xv[p >> 1];
        return (p & 1) ? hihalf(v) : lohalf(v);
    };

    // one skewed step: L0 + (skewed) L1, then one batched LDS exchange
    auto full_step = [&](float xpm) {
        // ---- L0 dot: a = xpm + wh0 . h1 (10 pk_fma) ----
        v2f aE = (v2f){xpm, 0.f}, aO = (v2f){0.f, 0.f};
        #pragma unroll
        for (int k = 0; k < H_ / 2; k += 2) {
            aE = pkfma(h1p[k],     wh0p[k],     aE);
            aO = pkfma(h1p[k + 1], wh0p[k + 1], aO);
        }
        v2f as = aE + aO;
        float h1n = fast_tanh(as.x + as.y);
        CFENCE();
        h1s[slc][i] = h1n;
        CFENCE();

        // ---- L1 dots (skewed; register-only): 20 pk_fma ----
        v2f bE = (v2f){bias1, 0.f}, bO = (v2f){0.f, 0.f};
        #pragma unroll
        for (int k = 0; k < H_ / 2; k += 2) {
            bE = pkfma(h1p[k],     wi1p[k],     bE);
            bO = pkfma(h1p[k + 1], wi1p[k + 1], bO);
        }
        #pragma unroll
        for (int k = 0; k < H_ / 2; k += 2) {
            bE = pkfma(h2p[k],     wh1p[k],     bE);
            bO = pkfma(h2p[k + 1], wh1p[k + 1], bO);
        }
        v2f bs = bE + bO;
        float h2n = fast_tanh(bs.x + bs.y);
        CFENCE();
        h2s[slc][i] = h2n;
        CFENCE();

        // ---- batched readback (h2 wait covered by next step's L0) ----
        #pragma unroll
        for (int k = 0; k < H_ / 4; ++k) {
            v4f v = reinterpret_cast<const v4f*>(&h1s[slc][0])[k];
            h1p[2*k] = lohalf(v); h1p[2*k+1] = hihalf(v);
        }
        #pragma unroll
        for (int k = 0; k < H_ / 4; ++k) {
            v4f v = reinterpret_cast<const v4f*>(&h2s[slc][0])[k];
            h2p[2*k] = lohalf(v); h2p[2*k+1] = hihalf(v);
        }
        CFENCE();
    };

    // consume xv -> xp for a chunk (5 pk_fma + 1 add per step)
    auto consume_xp = [&](float (&xp)[CH]) {
        #pragma unroll
        for (int m = 0; m < CH; ++m) {
            v2f acc = (v2f){bias0, 0.f};
            #pragma unroll
            for (int q = 0; q < DIN / 2; ++q)
                acc = pkfma(getpair(m * (DIN / 2) + q), wi0p[q], acc);
            xp[m] = acc.x + acc.y;
        }
    };

    // ---- chunk 0 (tau = 0..CH-1), tau=0 peeled: h1(0)=tanh(xp[0]) ----
    {
        float xp[CH];
        consume_xp(xp);
        #pragma unroll
        for (int k = 0; k < XV; ++k) xv[k] = xb[(CH * DIN) / 4 + k];  // prefetch chunk 1

        float h1n = fast_tanh(xp[0]);
        CFENCE();
        h1s[slc][i] = h1n;
        CFENCE();
        #pragma unroll
        for (int k = 0; k < H_ / 4; ++k) {
            v4f v = reinterpret_cast<const v4f*>(&h1s[slc][0])[k];
            h1p[2*k] = lohalf(v); h1p[2*k+1] = hihalf(v);
        }
        CFENCE();

        #pragma unroll
        for (int m = 1; m < CH; ++m) full_step(xp[m]);
    }

    // ---- main loop: chunks t0 = CH .. T-CH ----
    for (int t0 = CH; t0 < T_; t0 += CH) {
        float xp[CH];
        consume_xp(xp);
        {
            const int t0n = (t0 + CH < T_) ? (t0 + CH) : 0;  // clamp, branchless
            #pragma unroll
            for (int k = 0; k < XV; ++k) xv[k] = xb[(t0n * DIN) / 4 + k];
        }
        #pragma unroll
        for (int m = 0; m < CH; ++m) full_step(xp[m]);
    }

    // ---- epilogue: h2(T-1) from h1(T-1) (=h1p) and h2(T-2) (=h2p) ----
    {
        v2f bE = (v2f){bias1, 0.f}, bO = (v2f){0.f, 0.f};
        #pragma unroll
        for (int k = 0; k < H_ / 2; k += 2) {
            bE = pkfma(h1p[k],     wi1p[k],     bE);
            bO = pkfma(h1p[k + 1], wi1p[k + 1], bO);
        }
        #pragma unroll
        for (int k = 0; k < H_ / 2; k += 2) {
            bE = pkfma(h2p[k],     wh1p[k],     bE);
            bO = pkfma(h2p[k + 1], wh1p[k + 1], bO);
        }
        v2f bs = bE + bO;
        float h2n = fast_tanh(bs.x + bs.y);
        CFENCE();
        h2s[slc][i] = h2n;
        CFENCE();
        #pragma unroll
        for (int k = 0; k < H_ / 4; ++k) {
            v4f v = reinterpret_cast<const v4f*>(&h2s[slc][0])[k];
            h2p[2*k] = lohalf(v); h2p[2*k+1] = hihalf(v);
        }
        CFENCE();
    }

    // ---- FC: lanes i<2 hold full h2(T-1); out[samp][i] ----
    if (sl < SPW && samp < B_ && i < DOUT) {
        const v2f* fw = reinterpret_cast<const v2f*>(fc_w + i * H_);
        v2f acc = (v2f){fc_b[i], 0.f};
        #pragma unroll
        for (int k = 0; k < H_ / 2; ++k) acc = pkfma(h2p[k], fw[k], acc);
        out[samp * DOUT + i] = acc.x + acc.y;
    }
}

extern "C" void kernel_launch(void* const* d_in, const int* in_sizes, int n_in,
                              void* d_out, int out_size, void* d_ws, size_t ws_size,
                              hipStream_t stream) {
    (void)in_sizes; (void)n_in; (void)d_ws; (void)ws_size; (void)out_size;
    const float* x     = (const float*)d_in[0];
    const float* w_ih0 = (const float*)d_in[1];
    const float* w_hh0 = (const float*)d_in[2];
    const float* b_ih0 = (const float*)d_in[3];
    const float* b_hh0 = (const float*)d_in[4];
    const float* w_ih1 = (const float*)d_in[5];
    const float* w_hh1 = (const float*)d_in[6];
    const float* b_ih1 = (const float*)d_in[7];
    const float* b_hh1 = (const float*)d_in[8];
    const float* fc_w  = (const float*)d_in[9];
    const float* fc_b  = (const float*)d_in[10];
    float* out = (float*)d_out;

    const int grid = (B_ + SPW - 1) / SPW;   // 1366 single-wave blocks
    hipLaunchKernelGGL(rnn_pk, dim3(grid), dim3(64), 0, stream,
                       x, w_ih0, w_hh0, b_ih0, b_hh0,
                       w_ih1, w_hh1, b_ih1, b_hh1, fc_w, fc_b, out);
}